// Round 1
// baseline (1202.987 us; speedup 1.0000x reference)
//
#include <hip/hip_runtime.h>
#include <math.h>

#define NB 16
#define SEQ 512
#define DIM 512
#define NH 8
#define DHEAD 64
#define MROWS (NB*SEQ)   // 8192

// ---------------------------------------------------------------------------
// Kernel 1: per-row mean/rstd for the three LN'd inputs (q,k,v)
// stats layout: [which][row][2] -> mean, rstd
// ---------------------------------------------------------------------------
__global__ __launch_bounds__(128)
void row_stats_kernel(const float* __restrict__ q, const float* __restrict__ k,
                      const float* __restrict__ v, float* __restrict__ stats) {
    const int row = blockIdx.x;     // 0..8191
    const int which = blockIdx.y;   // 0..2
    const float* src = (which == 0) ? q : ((which == 1) ? k : v);
    const float4* p = (const float4*)(src + (size_t)row * DIM);
    const int t = threadIdx.x;      // 128 threads, 4 floats each = 512
    float4 a = p[t];
    float s  = a.x + a.y + a.z + a.w;
    float ss = a.x*a.x + a.y*a.y + a.z*a.z + a.w*a.w;
    #pragma unroll
    for (int off = 32; off > 0; off >>= 1) {
        s  += __shfl_down(s,  off);
        ss += __shfl_down(ss, off);
    }
    __shared__ float red[4];
    if ((t & 63) == 0) { red[(t >> 6)*2 + 0] = s; red[(t >> 6)*2 + 1] = ss; }
    __syncthreads();
    if (t == 0) {
        float S  = red[0] + red[2];
        float SS = red[1] + red[3];
        float mean = S * (1.0f / DIM);
        float var  = SS * (1.0f / DIM) - mean * mean;
        stats[((size_t)which * MROWS + row)*2 + 0] = mean;
        stats[((size_t)which * MROWS + row)*2 + 1] = rsqrtf(var + 1e-5f);
    }
}

// ---------------------------------------------------------------------------
// Kernel 2: C[M,N] = A'[M,K] @ W[N,K]^T   (M=8192, N=K=512)
// A' = LN(A) (fused via stats + gamma/beta) when LN=true, else A' = A.
// Tile 64x64, BK=16, 256 threads, 4x4 micro-tile, reg-prefetch next slab.
// ---------------------------------------------------------------------------
template<bool LN>
__global__ __launch_bounds__(256)
void gemm_nt_kernel(const float* __restrict__ A, const float* __restrict__ W,
                    float* __restrict__ C, const float* __restrict__ stats,
                    const float* __restrict__ gamma, const float* __restrict__ beta) {
    __shared__ float As[16][68];   // transposed: [k][m], odd-16B stride
    __shared__ float Bs[16][68];
    const int tid = threadIdx.x;
    const int bm = blockIdx.x, bn = blockIdx.y;
    const int lrow = tid >> 2;            // 0..63 tile row
    const int lc4  = tid & 3;             // 0..3  float4 col within BK=16
    const int arow = bm*64 + lrow;
    const int wrow = bn*64 + lrow;
    float mean = 0.f, rstd = 0.f;
    if (LN) { mean = stats[arow*2 + 0]; rstd = stats[arow*2 + 1]; }
    const int ty = tid >> 4;              // 0..15
    const int tx = tid & 15;              // 0..15
    float acc[4][4] = {};
    const float4* Arow4 = (const float4*)(A + (size_t)arow * DIM);
    const float4* Wrow4 = (const float4*)(W + (size_t)wrow * DIM);

    float4 av = Arow4[lc4];
    float4 wvv = Wrow4[lc4];
    for (int kt = 0; kt < DIM/16; ++kt) {
        if (LN) {
            const float4 gv = *(const float4*)(gamma + kt*16 + lc4*4);
            const float4 bv = *(const float4*)(beta  + kt*16 + lc4*4);
            av.x = (av.x - mean)*rstd*gv.x + bv.x;
            av.y = (av.y - mean)*rstd*gv.y + bv.y;
            av.z = (av.z - mean)*rstd*gv.z + bv.z;
            av.w = (av.w - mean)*rstd*gv.w + bv.w;
        }
        __syncthreads();
        const int kc = lc4*4;
        As[kc+0][lrow] = av.x;  As[kc+1][lrow] = av.y;
        As[kc+2][lrow] = av.z;  As[kc+3][lrow] = av.w;
        Bs[kc+0][lrow] = wvv.x; Bs[kc+1][lrow] = wvv.y;
        Bs[kc+2][lrow] = wvv.z; Bs[kc+3][lrow] = wvv.w;
        __syncthreads();
        float4 av_n, wv_n;
        if (kt < DIM/16 - 1) {           // prefetch next slab during compute
            av_n = Arow4[(kt+1)*4 + lc4];
            wv_n = Wrow4[(kt+1)*4 + lc4];
        }
        #pragma unroll
        for (int kk = 0; kk < 16; ++kk) {
            const float4 a4 = *(const float4*)&As[kk][ty*4];
            const float4 b4 = *(const float4*)&Bs[kk][tx*4];
            const float ar[4] = {a4.x, a4.y, a4.z, a4.w};
            const float br[4] = {b4.x, b4.y, b4.z, b4.w};
            #pragma unroll
            for (int i = 0; i < 4; ++i)
                #pragma unroll
                for (int j = 0; j < 4; ++j)
                    acc[i][j] = fmaf(ar[i], br[j], acc[i][j]);
        }
        if (kt < DIM/16 - 1) { av = av_n; wvv = wv_n; }
    }
    #pragma unroll
    for (int i = 0; i < 4; ++i) {
        float4 o = make_float4(acc[i][0], acc[i][1], acc[i][2], acc[i][3]);
        *(float4*)(C + (size_t)(bm*64 + ty*4 + i)*DIM + bn*64 + tx*4) = o;
    }
}

// ---------------------------------------------------------------------------
// Kernel 3: attention. Block = (qt, h, b), q-tile = 16 rows.
//   S = (Q K^T)/8, diag-masked softmax, P -> attn_out (head-major layout),
//   dynpre = P @ V.  LDS: S 33KB + K/V 17.4KB + Q 4.4KB = 54.7KB (<64KB).
// ---------------------------------------------------------------------------
__global__ __launch_bounds__(256)
void attn_kernel(const float* __restrict__ qh, const float* __restrict__ kh,
                 const float* __restrict__ vh, float* __restrict__ attn_out,
                 float* __restrict__ dynpre) {
    __shared__ float S[16][516];    // +4 pad: breaks 2KB-stride bank aliasing
    __shared__ float Ks[64][68];    // K chunk; reused as V chunk in phase 3
    __shared__ float Qs[16][68];
    const int tid = threadIdx.x;
    const int qt = blockIdx.x;      // 0..31
    const int h  = blockIdx.y;      // 0..7
    const int b  = blockIdx.z;      // 0..15
    const int q0 = qt * 16;
    const int lane = tid & 63;
    const int wv   = tid >> 6;      // wave id 0..3

    {   // load Q tile [16][64]
        const int row = tid >> 4, c4 = tid & 15;
        *(float4*)&Qs[row][c4*4] =
            *(const float4*)(qh + (size_t)(b*SEQ + q0 + row)*DIM + h*DHEAD + c4*4);
    }

    // ---- phase 1: S = Q K^T, 8 chunks of 64 k-columns -------------------
    for (int kc = 0; kc < 8; ++kc) {
        __syncthreads();            // previous chunk's Ks reads done (also covers Qs)
        #pragma unroll
        for (int it = 0; it < 4; ++it) {
            const int lin = tid + it*256;
            const int row = lin >> 4, c4 = lin & 15;
            *(float4*)&Ks[row][c4*4] =
                *(const float4*)(kh + (size_t)(b*SEQ + kc*64 + row)*DIM + h*DHEAD + c4*4);
        }
        __syncthreads();
        float acc[4] = {0.f, 0.f, 0.f, 0.f};
        #pragma unroll
        for (int d4 = 0; d4 < 16; ++d4) {
            const float4 kv = *(const float4*)&Ks[lane][d4*4];
            #pragma unroll
            for (int i = 0; i < 4; ++i) {
                const float4 qv = *(const float4*)&Qs[wv*4 + i][d4*4];  // wave-uniform: broadcast
                acc[i] += qv.x*kv.x + qv.y*kv.y + qv.z*kv.z + qv.w*kv.w;
            }
        }
        #pragma unroll
        for (int i = 0; i < 4; ++i) S[wv*4 + i][kc*64 + lane] = acc[i];
    }

    // ---- phase 2: softmax on own wave's rows (wave wrote exactly these) --
    float* arow_base = attn_out + ((size_t)(h*NB + b)*SEQ + q0)*SEQ;
    #pragma unroll
    for (int rr = 0; rr < 4; ++rr) {
        const int r = wv*4 + rr;
        const int qglob = q0 + r;
        float vals[8];
        float4 lo = *(const float4*)&S[r][lane*4];
        float4 hi = *(const float4*)&S[r][256 + lane*4];
        vals[0]=lo.x; vals[1]=lo.y; vals[2]=lo.z; vals[3]=lo.w;
        vals[4]=hi.x; vals[5]=hi.y; vals[6]=hi.z; vals[7]=hi.w;
        #pragma unroll
        for (int j = 0; j < 8; ++j) vals[j] *= 0.125f;
        #pragma unroll
        for (int j = 0; j < 4; ++j) {         // diagonal mask
            if (lane*4 + j == qglob)       vals[j]   = -1e30f;
            if (256 + lane*4 + j == qglob) vals[4+j] = -1e30f;
        }
        float mx = vals[0];
        #pragma unroll
        for (int j = 1; j < 8; ++j) mx = fmaxf(mx, vals[j]);
        #pragma unroll
        for (int off = 32; off > 0; off >>= 1) mx = fmaxf(mx, __shfl_xor(mx, off));
        float sum = 0.f;
        #pragma unroll
        for (int j = 0; j < 8; ++j) { vals[j] = __expf(vals[j] - mx); sum += vals[j]; }
        #pragma unroll
        for (int off = 32; off > 0; off >>= 1) sum += __shfl_xor(sum, off);
        const float inv = 1.0f / sum;
        #pragma unroll
        for (int j = 0; j < 8; ++j) vals[j] *= inv;
        lo = make_float4(vals[0], vals[1], vals[2], vals[3]);
        hi = make_float4(vals[4], vals[5], vals[6], vals[7]);
        *(float4*)&S[r][lane*4]       = lo;   // keep P for PV
        *(float4*)&S[r][256 + lane*4] = hi;
        *(float4*)(arow_base + (size_t)r*SEQ + lane*4)       = lo;   // coalesced P out
        *(float4*)(arow_base + (size_t)r*SEQ + 256 + lane*4) = hi;
    }

    // ---- phase 3: dynpre = P @ V ----------------------------------------
    const int pq = tid >> 4;   // 0..15 : q row
    const int dg = tid & 15;   // 0..15 : d float4 group (coalesced store)
    float4 oacc = {0.f, 0.f, 0.f, 0.f};
    for (int vc = 0; vc < 8; ++vc) {
        __syncthreads();       // all P writes done / previous V reads done
        #pragma unroll
        for (int it = 0; it < 4; ++it) {
            const int lin = tid + it*256;
            const int row = lin >> 4, c4 = lin & 15;
            *(float4*)&Ks[row][c4*4] =
                *(const float4*)(vh + (size_t)(b*SEQ + vc*64 + row)*DIM + h*DHEAD + c4*4);
        }
        __syncthreads();
        #pragma unroll
        for (int k = 0; k < 64; ++k) {
            const float  p    = S[pq][vc*64 + k];                  // 4-addr broadcast
            const float4 vvec = *(const float4*)&Ks[k][dg*4];
            oacc.x = fmaf(p, vvec.x, oacc.x);
            oacc.y = fmaf(p, vvec.y, oacc.y);
            oacc.z = fmaf(p, vvec.z, oacc.z);
            oacc.w = fmaf(p, vvec.w, oacc.w);
        }
    }
    *(float4*)(dynpre + (size_t)(b*SEQ + q0 + pq)*DIM + h*DHEAD + dg*4) = oacc;
}

// ---------------------------------------------------------------------------
extern "C" void kernel_launch(void* const* d_in, const int* in_sizes, int n_in,
                              void* d_out, int out_size, void* d_ws, size_t ws_size,
                              hipStream_t stream) {
    const float* q    = (const float*)d_in[0];
    const float* k    = (const float*)d_in[1];
    const float* v    = (const float*)d_in[2];
    const float* Wq   = (const float*)d_in[3];
    const float* Wk   = (const float*)d_in[4];
    const float* Wv   = (const float*)d_in[5];
    const float* fc1  = (const float*)d_in[6];
    const float* fc2  = (const float*)d_in[7];
    const float* ln1g = (const float*)d_in[8];
    const float* ln1b = (const float*)d_in[9];
    const float* ln2g = (const float*)d_in[10];
    const float* ln2b = (const float*)d_in[11];
    const float* ln3g = (const float*)d_in[12];
    const float* ln3b = (const float*)d_in[13];

    float* ws     = (float*)d_ws;
    float* stats  = ws;                       // 3*8192*2 = 49152 floats
    float* qh     = ws + 65536;               // [8192][512] each
    float* kh     = qh + (size_t)MROWS*DIM;
    float* vh     = kh + (size_t)MROWS*DIM;
    float* dynpre = vh + (size_t)MROWS*DIM;   // total ws use ~64.3 MB

    float* outDyn  = (float*)d_out;                    // [16,512,512]
    float* outStat = outDyn + (size_t)MROWS*DIM;       // [16,512,512]
    float* outAttn = outStat + (size_t)MROWS*DIM;      // [128,512,512]

    row_stats_kernel<<<dim3(MROWS, 3), 128, 0, stream>>>(q, k, v, stats);

    const dim3 gg(MROWS/64, DIM/64);   // 128 x 8
    gemm_nt_kernel<true ><<<gg, 256, 0, stream>>>(q, Wq, qh, stats + 0*2*MROWS, ln1g, ln1b);
    gemm_nt_kernel<true ><<<gg, 256, 0, stream>>>(k, Wk, kh, stats + 1*2*MROWS, ln2g, ln2b);
    gemm_nt_kernel<true ><<<gg, 256, 0, stream>>>(v, Wv, vh, stats + 2*2*MROWS, ln3g, ln3b);

    attn_kernel<<<dim3(SEQ/16, NH, NB), 256, 0, stream>>>(qh, kh, vh, outAttn, dynpre);

    gemm_nt_kernel<false><<<gg, 256, 0, stream>>>(dynpre, fc1, outDyn,  nullptr, nullptr, nullptr);
    gemm_nt_kernel<false><<<gg, 256, 0, stream>>>(vh,     fc2, outStat, nullptr, nullptr, nullptr);
}

// Round 2
// 589.865 us; speedup vs baseline: 2.0394x; 2.0394x over previous
//
#include <hip/hip_runtime.h>
#include <hip/hip_bf16.h>
#include <math.h>

#define NB 16
#define SEQ 512
#define DIM 512
#define NH 8
#define DHEAD 64
#define MROWS (NB*SEQ)   // 8192

typedef __bf16 bf16x8 __attribute__((ext_vector_type(8)));
typedef float  f32x4  __attribute__((ext_vector_type(4)));

// ---------------------------------------------------------------------------
// Kernel 1: per-row mean/rstd for the three LN'd inputs (q,k,v)
// ---------------------------------------------------------------------------
__global__ __launch_bounds__(128)
void row_stats_kernel(const float* __restrict__ q, const float* __restrict__ k,
                      const float* __restrict__ v, float* __restrict__ stats) {
    const int row = blockIdx.x;
    const int which = blockIdx.y;
    const float* src = (which == 0) ? q : ((which == 1) ? k : v);
    const float4* p = (const float4*)(src + (size_t)row * DIM);
    const int t = threadIdx.x;
    float4 a = p[t];
    float s  = a.x + a.y + a.z + a.w;
    float ss = a.x*a.x + a.y*a.y + a.z*a.z + a.w*a.w;
    #pragma unroll
    for (int off = 32; off > 0; off >>= 1) {
        s  += __shfl_down(s,  off);
        ss += __shfl_down(ss, off);
    }
    __shared__ float red[4];
    if ((t & 63) == 0) { red[(t >> 6)*2 + 0] = s; red[(t >> 6)*2 + 1] = ss; }
    __syncthreads();
    if (t == 0) {
        float S  = red[0] + red[2];
        float SS = red[1] + red[3];
        float mean = S * (1.0f / DIM);
        float var  = SS * (1.0f / DIM) - mean * mean;
        stats[((size_t)which * MROWS + row)*2 + 0] = mean;
        stats[((size_t)which * MROWS + row)*2 + 1] = rsqrtf(var + 1e-5f);
    }
}

// ---------------------------------------------------------------------------
// Kernel 2: C[M,N] = A'[M,K] @ W[N,K]^T  with optional fp32 / bf16 / bf16-V^T
// outputs. V^T layout: [(b*NH + h)*DHEAD + d][seq]  (per-head transposed).
// ---------------------------------------------------------------------------
template<bool LN, bool F32OUT, bool BF16OUT, bool VTOUT>
__global__ __launch_bounds__(256)
void gemm_nt_kernel(const float* __restrict__ A, const float* __restrict__ W,
                    float* __restrict__ C, const float* __restrict__ stats,
                    const float* __restrict__ gamma, const float* __restrict__ beta,
                    __hip_bfloat16* __restrict__ Cb, __hip_bfloat16* __restrict__ CvT) {
    __shared__ float As[16][68];
    __shared__ float Bs[16][68];
    const int tid = threadIdx.x;
    const int bm = blockIdx.x, bn = blockIdx.y;
    const int lrow = tid >> 2;
    const int lc4  = tid & 3;
    const int arow = bm*64 + lrow;
    const int wrow = bn*64 + lrow;
    float mean = 0.f, rstd = 0.f;
    if (LN) { mean = stats[arow*2 + 0]; rstd = stats[arow*2 + 1]; }
    const int ty = tid >> 4;
    const int tx = tid & 15;
    float acc[4][4] = {};
    const float4* Arow4 = (const float4*)(A + (size_t)arow * DIM);
    const float4* Wrow4 = (const float4*)(W + (size_t)wrow * DIM);

    float4 av = Arow4[lc4];
    float4 wvv = Wrow4[lc4];
    for (int kt = 0; kt < DIM/16; ++kt) {
        if (LN) {
            const float4 gv = *(const float4*)(gamma + kt*16 + lc4*4);
            const float4 bv = *(const float4*)(beta  + kt*16 + lc4*4);
            av.x = (av.x - mean)*rstd*gv.x + bv.x;
            av.y = (av.y - mean)*rstd*gv.y + bv.y;
            av.z = (av.z - mean)*rstd*gv.z + bv.z;
            av.w = (av.w - mean)*rstd*gv.w + bv.w;
        }
        __syncthreads();
        const int kc = lc4*4;
        As[kc+0][lrow] = av.x;  As[kc+1][lrow] = av.y;
        As[kc+2][lrow] = av.z;  As[kc+3][lrow] = av.w;
        Bs[kc+0][lrow] = wvv.x; Bs[kc+1][lrow] = wvv.y;
        Bs[kc+2][lrow] = wvv.z; Bs[kc+3][lrow] = wvv.w;
        __syncthreads();
        float4 av_n, wv_n;
        if (kt < DIM/16 - 1) {
            av_n = Arow4[(kt+1)*4 + lc4];
            wv_n = Wrow4[(kt+1)*4 + lc4];
        }
        #pragma unroll
        for (int kk = 0; kk < 16; ++kk) {
            const float4 a4 = *(const float4*)&As[kk][ty*4];
            const float4 b4 = *(const float4*)&Bs[kk][tx*4];
            const float ar[4] = {a4.x, a4.y, a4.z, a4.w};
            const float br[4] = {b4.x, b4.y, b4.z, b4.w};
            #pragma unroll
            for (int i = 0; i < 4; ++i)
                #pragma unroll
                for (int j = 0; j < 4; ++j)
                    acc[i][j] = fmaf(ar[i], br[j], acc[i][j]);
        }
        if (kt < DIM/16 - 1) { av = av_n; wvv = wv_n; }
    }
    #pragma unroll
    for (int i = 0; i < 4; ++i) {
        const int row = bm*64 + ty*4 + i;
        if (F32OUT) {
            float4 o = make_float4(acc[i][0], acc[i][1], acc[i][2], acc[i][3]);
            *(float4*)(C + (size_t)row*DIM + bn*64 + tx*4) = o;
        }
        if (BF16OUT) {
            union { ushort4 u; __hip_bfloat16 h[4]; } cv;
            cv.h[0] = __float2bfloat16(acc[i][0]);
            cv.h[1] = __float2bfloat16(acc[i][1]);
            cv.h[2] = __float2bfloat16(acc[i][2]);
            cv.h[3] = __float2bfloat16(acc[i][3]);
            *(ushort4*)(Cb + (size_t)row*DIM + bn*64 + tx*4) = cv.u;
        }
    }
    if (VTOUT) {
        // rows of this tile are 64 consecutive seq positions within one batch
        // (bm>>3 = b); cols are one head (bn = h), d = tx*4+j.
        #pragma unroll
        for (int j = 0; j < 4; ++j) {
            union { ushort4 u; __hip_bfloat16 h[4]; } cv;
            cv.h[0] = __float2bfloat16(acc[0][j]);
            cv.h[1] = __float2bfloat16(acc[1][j]);
            cv.h[2] = __float2bfloat16(acc[2][j]);
            cv.h[3] = __float2bfloat16(acc[3][j]);
            size_t idx = ((size_t)((bm>>3)*NH + bn)*DHEAD + tx*4 + j)*SEQ
                       + (bm&7)*64 + ty*4;
            *(ushort4*)(CvT + idx) = cv.u;
        }
    }
}

// ---------------------------------------------------------------------------
// Kernel 3: MFMA attention. Block = (qt 16 rows, h, b), 4 waves.
// Wave w: S[16][w*128..w*128+128) via 16 mfma_16x16x32_bf16, frags direct
// from global (K row-major, V pre-transposed). Softmax in regs (shfl within
// 16-lane groups + tiny LDS cross-wave). P -> attn_out (fp32 from regs) and
// -> 16KB XOR-swizzled LDS (bf16) for the PV MFMAs.
// ---------------------------------------------------------------------------
__global__ __launch_bounds__(256)
void attn_mfma_kernel(const __hip_bfloat16* __restrict__ qhb,
                      const __hip_bfloat16* __restrict__ khb,
                      const __hip_bfloat16* __restrict__ vhT,
                      float* __restrict__ attn_out,
                      float* __restrict__ dynpre) {
    __shared__ __hip_bfloat16 P_lds[16*512];   // 16KB, XOR-swizzled
    __shared__ float redbuf[2][4][16];
    const int tid = threadIdx.x;
    const int qt = blockIdx.x, h = blockIdx.y, b = blockIdx.z;
    const int q0 = qt * 16;
    const int w  = tid >> 6;
    const int l  = tid & 63;
    const int lr = l & 15;    // A/B frag: row/col lane; C/D frag: column lane
    const int lg = l >> 4;    // k-group

    // Q fragments (A): lane holds Q[q0+lr][d = 32*ks + 8*lg + j]
    const size_t qoff = (size_t)(b*SEQ + q0 + lr)*DIM + h*DHEAD + lg*8;
    const bf16x8 qf0 = *(const bf16x8*)(qhb + qoff);
    const bf16x8 qf1 = *(const bf16x8*)(qhb + qoff + 32);

    // ---- phase 1: S strip for cols [w*128, w*128+128) --------------------
    f32x4 acc[8];
    #pragma unroll
    for (int t = 0; t < 8; ++t) acc[t] = (f32x4){0.f, 0.f, 0.f, 0.f};
    #pragma unroll
    for (int t = 0; t < 8; ++t) {
        const int kbase = w*128 + t*16;
        const size_t koff = (size_t)(b*SEQ + kbase + lr)*DIM + h*DHEAD + lg*8;
        const bf16x8 kf0 = *(const bf16x8*)(khb + koff);
        const bf16x8 kf1 = *(const bf16x8*)(khb + koff + 32);
        acc[t] = __builtin_amdgcn_mfma_f32_16x16x32_bf16(qf0, kf0, acc[t], 0, 0, 0);
        acc[t] = __builtin_amdgcn_mfma_f32_16x16x32_bf16(qf1, kf1, acc[t], 0, 0, 0);
    }
    // lane now holds S[q = lg*4 + r][col = w*128 + t*16 + lr] (C/D layout)

    // ---- phase 2: scale, diagonal mask, softmax --------------------------
    float m[4];
    #pragma unroll
    for (int r = 0; r < 4; ++r) {
        const int grow = q0 + lg*4 + r;
        float mx = -1e30f;
        #pragma unroll
        for (int t = 0; t < 8; ++t) {
            float vv = acc[t][r] * 0.125f;
            if (w*128 + t*16 + lr == grow) vv = -1e30f;
            acc[t][r] = vv;
            mx = fmaxf(mx, vv);
        }
        #pragma unroll
        for (int off = 1; off < 16; off <<= 1) mx = fmaxf(mx, __shfl_xor(mx, off));
        m[r] = mx;
    }
    if (lr == 0) redbuf[0][w][lg*4+0] = m[0];
    if (lr == 1) redbuf[0][w][lg*4+1] = m[1];
    if (lr == 2) redbuf[0][w][lg*4+2] = m[2];
    if (lr == 3) redbuf[0][w][lg*4+3] = m[3];
    __syncthreads();
    float s[4];
    #pragma unroll
    for (int r = 0; r < 4; ++r) {
        const int rr = lg*4 + r;
        const float mx = fmaxf(fmaxf(redbuf[0][0][rr], redbuf[0][1][rr]),
                               fmaxf(redbuf[0][2][rr], redbuf[0][3][rr]));
        float sum = 0.f;
        #pragma unroll
        for (int t = 0; t < 8; ++t) {
            const float e = __expf(acc[t][r] - mx);
            acc[t][r] = e;
            sum += e;
        }
        #pragma unroll
        for (int off = 1; off < 16; off <<= 1) sum += __shfl_xor(sum, off);
        s[r] = sum;
    }
    if (lr == 0) redbuf[1][w][lg*4+0] = s[0];
    if (lr == 1) redbuf[1][w][lg*4+1] = s[1];
    if (lr == 2) redbuf[1][w][lg*4+2] = s[2];
    if (lr == 3) redbuf[1][w][lg*4+3] = s[3];
    __syncthreads();

    // ---- phase 3: normalize, write attn_out (fp32) + P_lds (bf16) --------
    float* arow = attn_out + ((size_t)(h*NB + b)*SEQ + q0)*SEQ + w*128;
    #pragma unroll
    for (int r = 0; r < 4; ++r) {
        const int rr = lg*4 + r;
        const float inv = 1.0f / (redbuf[1][0][rr] + redbuf[1][1][rr] +
                                  redbuf[1][2][rr] + redbuf[1][3][rr]);
        #pragma unroll
        for (int t = 0; t < 8; ++t) {
            const float p = acc[t][r] * inv;
            arow[(size_t)rr*SEQ + t*16 + lr] = p;
            const int col = w*128 + t*16 + lr;
            int byte = rr*1024 + col*2;
            byte ^= (rr & 7) << 4;                       // st-16 XOR swizzle
            *(__hip_bfloat16*)((char*)P_lds + byte) = __float2bfloat16(p);
        }
    }
    __syncthreads();

    // ---- phase 4: dynpre tile [16 q][16 d] per wave via 16 MFMA ----------
    f32x4 oa = (f32x4){0.f, 0.f, 0.f, 0.f};
    f32x4 ob = (f32x4){0.f, 0.f, 0.f, 0.f};
    const size_t vbase = ((size_t)(b*NH + h)*DHEAD + w*16 + lr)*SEQ;
    #pragma unroll
    for (int ks = 0; ks < 16; ks += 2) {
        int byte0 = lr*1024 + ks*64 + lg*16;
        byte0 ^= (lr & 7) << 4;
        const bf16x8 pa0 = *(const bf16x8*)((char*)P_lds + byte0);
        const bf16x8 pb0 = *(const bf16x8*)(vhT + vbase + ks*32 + lg*8);
        oa = __builtin_amdgcn_mfma_f32_16x16x32_bf16(pa0, pb0, oa, 0, 0, 0);
        int byte1 = lr*1024 + (ks+1)*64 + lg*16;
        byte1 ^= (lr & 7) << 4;
        const bf16x8 pa1 = *(const bf16x8*)((char*)P_lds + byte1);
        const bf16x8 pb1 = *(const bf16x8*)(vhT + vbase + (ks+1)*32 + lg*8);
        ob = __builtin_amdgcn_mfma_f32_16x16x32_bf16(pa1, pb1, ob, 0, 0, 0);
    }
    #pragma unroll
    for (int r = 0; r < 4; ++r) {
        dynpre[(size_t)(b*SEQ + q0 + lg*4 + r)*DIM + h*DHEAD + w*16 + lr]
            = oa[r] + ob[r];
    }
}

// ---------------------------------------------------------------------------
extern "C" void kernel_launch(void* const* d_in, const int* in_sizes, int n_in,
                              void* d_out, int out_size, void* d_ws, size_t ws_size,
                              hipStream_t stream) {
    const float* q    = (const float*)d_in[0];
    const float* k    = (const float*)d_in[1];
    const float* v    = (const float*)d_in[2];
    const float* Wq   = (const float*)d_in[3];
    const float* Wk   = (const float*)d_in[4];
    const float* Wv   = (const float*)d_in[5];
    const float* fc1  = (const float*)d_in[6];
    const float* fc2  = (const float*)d_in[7];
    const float* ln1g = (const float*)d_in[8];
    const float* ln1b = (const float*)d_in[9];
    const float* ln2g = (const float*)d_in[10];
    const float* ln2b = (const float*)d_in[11];
    const float* ln3g = (const float*)d_in[12];
    const float* ln3b = (const float*)d_in[13];

    float* ws     = (float*)d_ws;
    float* stats  = ws;                                  // 49152 floats
    float* vh     = ws + 65536;                          // fp32 [8192][512]
    float* dynpre = vh + (size_t)MROWS*DIM;              // fp32 [8192][512]
    __hip_bfloat16* qhb = (__hip_bfloat16*)(dynpre + (size_t)MROWS*DIM);
    __hip_bfloat16* khb = qhb + (size_t)MROWS*DIM;
    __hip_bfloat16* vhT = khb + (size_t)MROWS*DIM;       // total ~57.8 MB

    float* outDyn  = (float*)d_out;
    float* outStat = outDyn + (size_t)MROWS*DIM;
    float* outAttn = outStat + (size_t)MROWS*DIM;

    row_stats_kernel<<<dim3(MROWS, 3), 128, 0, stream>>>(q, k, v, stats);

    const dim3 gg(MROWS/64, DIM/64);
    // q,k projections: bf16 output only
    gemm_nt_kernel<true, false, true, false><<<gg, 256, 0, stream>>>(
        q, Wq, nullptr, stats + 0*2*MROWS, ln1g, ln1b, qhb, nullptr);
    gemm_nt_kernel<true, false, true, false><<<gg, 256, 0, stream>>>(
        k, Wk, nullptr, stats + 1*2*MROWS, ln2g, ln2b, khb, nullptr);
    // v projection: fp32 (for fc2) + bf16 per-head-transposed (for PV)
    gemm_nt_kernel<true, true, false, true><<<gg, 256, 0, stream>>>(
        v, Wv, vh, stats + 2*2*MROWS, ln3g, ln3b, nullptr, vhT);

    attn_mfma_kernel<<<dim3(SEQ/16, NH, NB), 256, 0, stream>>>(
        qhb, khb, vhT, outAttn, dynpre);

    gemm_nt_kernel<false, true, false, false><<<gg, 256, 0, stream>>>(
        dynpre, fc1, outDyn, nullptr, nullptr, nullptr, nullptr, nullptr);
    gemm_nt_kernel<false, true, false, false><<<gg, 256, 0, stream>>>(
        vh, fc2, outStat, nullptr, nullptr, nullptr, nullptr, nullptr);
}

// Round 3
// 358.945 us; speedup vs baseline: 3.3514x; 1.6433x over previous
//
#include <hip/hip_runtime.h>
#include <hip/hip_bf16.h>
#include <math.h>

#define NB 16
#define SEQ 512
#define DIM 512
#define NH 8
#define DHEAD 64
#define MROWS (NB*SEQ)   // 8192

typedef __bf16 bf16x8 __attribute__((ext_vector_type(8)));
typedef float  f32x4  __attribute__((ext_vector_type(4)));

typedef __attribute__((address_space(1))) const unsigned int gu32c;
typedef __attribute__((address_space(3))) unsigned int lu32;

__device__ __forceinline__ void gload_lds16(const void* g, void* l) {
    __builtin_amdgcn_global_load_lds((gu32c*)g, (lu32*)l, 16, 0, 0);
}

// ---------------------------------------------------------------------------
// Kernel 1: fused LayerNorm + bf16 cast. One block per (row, which).
// ---------------------------------------------------------------------------
__global__ __launch_bounds__(128)
void ln_fused_kernel(const float* __restrict__ q, const float* __restrict__ k,
                     const float* __restrict__ v,
                     const float* __restrict__ g0, const float* __restrict__ b0,
                     const float* __restrict__ g1, const float* __restrict__ b1,
                     const float* __restrict__ g2, const float* __restrict__ b2,
                     __hip_bfloat16* __restrict__ qn, __hip_bfloat16* __restrict__ kn,
                     __hip_bfloat16* __restrict__ vn) {
    const int row = blockIdx.x, which = blockIdx.y;
    const float* src = which==0 ? q : (which==1 ? k : v);
    const float* gp  = which==0 ? g0 : (which==1 ? g1 : g2);
    const float* bp  = which==0 ? b0 : (which==1 ? b1 : b2);
    __hip_bfloat16* dst = which==0 ? qn : (which==1 ? kn : vn);
    const int t = threadIdx.x;
    float4 a = *(const float4*)(src + (size_t)row*DIM + t*4);
    float s  = a.x + a.y + a.z + a.w;
    float ss = a.x*a.x + a.y*a.y + a.z*a.z + a.w*a.w;
    #pragma unroll
    for (int off = 32; off > 0; off >>= 1) {
        s  += __shfl_down(s,  off);
        ss += __shfl_down(ss, off);
    }
    __shared__ float red[4];
    if ((t & 63) == 0) { red[(t>>6)*2 + 0] = s; red[(t>>6)*2 + 1] = ss; }
    __syncthreads();
    const float S = red[0] + red[2], SS = red[1] + red[3];
    const float mean = S * (1.0f/DIM);
    const float rstd = rsqrtf(SS * (1.0f/DIM) - mean*mean + 1e-5f);
    const float4 gv = *(const float4*)(gp + t*4);
    const float4 bv = *(const float4*)(bp + t*4);
    union { ushort4 u; __hip_bfloat16 h[4]; } o;
    o.h[0] = __float2bfloat16((a.x-mean)*rstd*gv.x + bv.x);
    o.h[1] = __float2bfloat16((a.y-mean)*rstd*gv.y + bv.y);
    o.h[2] = __float2bfloat16((a.z-mean)*rstd*gv.z + bv.z);
    o.h[3] = __float2bfloat16((a.w-mean)*rstd*gv.w + bv.w);
    *(ushort4*)(dst + (size_t)row*DIM + t*4) = o.u;
}

// ---------------------------------------------------------------------------
// Kernel 2: fp32 -> bf16 cast of the 5 weight matrices (each 512x512).
// ---------------------------------------------------------------------------
__global__ __launch_bounds__(256)
void wconv_kernel(const float* __restrict__ w0, const float* __restrict__ w1,
                  const float* __restrict__ w2, const float* __restrict__ w3,
                  const float* __restrict__ w4, __hip_bfloat16* __restrict__ out) {
    const int m = blockIdx.y;
    const float* src = (m==0)?w0:(m==1)?w1:(m==2)?w2:(m==3)?w3:w4;
    __hip_bfloat16* dst = out + (size_t)m*DIM*DIM;
    const int i = (blockIdx.x*256 + threadIdx.x)*4;
    float4 x = *(const float4*)(src + i);
    union { ushort4 u; __hip_bfloat16 h[4]; } r;
    r.h[0]=__float2bfloat16(x.x); r.h[1]=__float2bfloat16(x.y);
    r.h[2]=__float2bfloat16(x.z); r.h[3]=__float2bfloat16(x.w);
    *(ushort4*)(dst + i) = r.u;
}

// ---------------------------------------------------------------------------
// Kernel 3: bf16 MFMA GEMM, C[M,N] = A[M,K] @ W[N,K]^T.  m97 structure:
// 128x128 tile, BK=32, 4 waves (2x2), global_load_lds w16, linear LDS
// (64B rows -> b128 frag reads are bank-uniform), 16 MFMA + 8 ds_read_b128
// per wave per K-step.
// ---------------------------------------------------------------------------
template<bool F32OUT, bool BF16OUT, bool VTOUT>
__global__ __launch_bounds__(256)
void gemm_mfma_kernel(const __hip_bfloat16* __restrict__ A,
                      const __hip_bfloat16* __restrict__ W,
                      float* __restrict__ Cf,
                      __hip_bfloat16* __restrict__ Cb,
                      __hip_bfloat16* __restrict__ CvT) {
    __shared__ __hip_bfloat16 Al[128*32];   // 8KB
    __shared__ __hip_bfloat16 Bl[128*32];   // 8KB
    const int tid = threadIdx.x;
    const int bm = blockIdx.x, bn = blockIdx.y;
    const int w = tid>>6, l = tid&63, lr = l&15, lg = l>>4;
    const int wr = w>>1, wc = w&1;
    const int grow = tid>>2, gslot = tid&3;   // 64 rows x 4 slots per issue
    f32x4 acc[4][4];
    #pragma unroll
    for (int mi=0; mi<4; ++mi)
        #pragma unroll
        for (int nj=0; nj<4; ++nj)
            acc[mi][nj] = (f32x4){0.f,0.f,0.f,0.f};
    const __hip_bfloat16* Ag = A + (size_t)(bm*128 + grow)*DIM + gslot*8;
    const __hip_bfloat16* Wg = W + (size_t)(bn*128 + grow)*DIM + gslot*8;

    for (int kt = 0; kt < 16; ++kt) {
        __syncthreads();   // prev iter's LDS reads drained before overwrite
        gload_lds16(Ag + kt*32,           (char*)Al + tid*16);
        gload_lds16(Ag + kt*32 + 64*DIM,  (char*)Al + 4096 + tid*16);
        gload_lds16(Wg + kt*32,           (char*)Bl + tid*16);
        gload_lds16(Wg + kt*32 + 64*DIM,  (char*)Bl + 4096 + tid*16);
        __syncthreads();   // compiler emits vmcnt(0) drain before barrier
        bf16x8 af[4], bg[4];
        #pragma unroll
        for (int mi=0; mi<4; ++mi)
            af[mi] = *(const bf16x8*)((char*)Al + (wr*64 + mi*16 + lr)*64 + lg*16);
        #pragma unroll
        for (int nj=0; nj<4; ++nj)
            bg[nj] = *(const bf16x8*)((char*)Bl + (wc*64 + nj*16 + lr)*64 + lg*16);
        #pragma unroll
        for (int mi=0; mi<4; ++mi)
            #pragma unroll
            for (int nj=0; nj<4; ++nj)
                acc[mi][nj] = __builtin_amdgcn_mfma_f32_16x16x32_bf16(
                    af[mi], bg[nj], acc[mi][nj], 0, 0, 0);
    }
    #pragma unroll
    for (int mi=0; mi<4; ++mi) {
        #pragma unroll
        for (int nj=0; nj<4; ++nj) {
            #pragma unroll
            for (int r=0; r<4; ++r) {
                const int row = bm*128 + wr*64 + mi*16 + lg*4 + r;
                const int col = bn*128 + wc*64 + nj*16 + lr;
                const float val = acc[mi][nj][r];
                if (F32OUT)  Cf[(size_t)row*DIM + col] = val;
                if (BF16OUT) Cb[(size_t)row*DIM + col] = __float2bfloat16(val);
                if (VTOUT) {
                    const int b = row >> 9, sp = row & 511;
                    const int h = col >> 6, d = col & 63;
                    CvT[((size_t)(b*NH + h)*DHEAD + d)*SEQ + sp] = __float2bfloat16(val);
                }
            }
        }
    }
}

// ---------------------------------------------------------------------------
// Kernel 4: MFMA attention (validated round 2). dynpre now bf16.
// ---------------------------------------------------------------------------
__global__ __launch_bounds__(256)
void attn_mfma_kernel(const __hip_bfloat16* __restrict__ qhb,
                      const __hip_bfloat16* __restrict__ khb,
                      const __hip_bfloat16* __restrict__ vhT,
                      float* __restrict__ attn_out,
                      __hip_bfloat16* __restrict__ dynb) {
    __shared__ __hip_bfloat16 P_lds[16*512];   // 16KB, XOR-swizzled
    __shared__ float redbuf[2][4][16];
    const int tid = threadIdx.x;
    const int qt = blockIdx.x, h = blockIdx.y, b = blockIdx.z;
    const int q0 = qt * 16;
    const int w  = tid >> 6;
    const int l  = tid & 63;
    const int lr = l & 15;
    const int lg = l >> 4;

    const size_t qoff = (size_t)(b*SEQ + q0 + lr)*DIM + h*DHEAD + lg*8;
    const bf16x8 qf0 = *(const bf16x8*)(qhb + qoff);
    const bf16x8 qf1 = *(const bf16x8*)(qhb + qoff + 32);

    f32x4 acc[8];
    #pragma unroll
    for (int t = 0; t < 8; ++t) acc[t] = (f32x4){0.f, 0.f, 0.f, 0.f};
    #pragma unroll
    for (int t = 0; t < 8; ++t) {
        const int kbase = w*128 + t*16;
        const size_t koff = (size_t)(b*SEQ + kbase + lr)*DIM + h*DHEAD + lg*8;
        const bf16x8 kf0 = *(const bf16x8*)(khb + koff);
        const bf16x8 kf1 = *(const bf16x8*)(khb + koff + 32);
        acc[t] = __builtin_amdgcn_mfma_f32_16x16x32_bf16(qf0, kf0, acc[t], 0, 0, 0);
        acc[t] = __builtin_amdgcn_mfma_f32_16x16x32_bf16(qf1, kf1, acc[t], 0, 0, 0);
    }

    float m[4];
    #pragma unroll
    for (int r = 0; r < 4; ++r) {
        const int grow = q0 + lg*4 + r;
        float mx = -1e30f;
        #pragma unroll
        for (int t = 0; t < 8; ++t) {
            float vv = acc[t][r] * 0.125f;
            if (w*128 + t*16 + lr == grow) vv = -1e30f;
            acc[t][r] = vv;
            mx = fmaxf(mx, vv);
        }
        #pragma unroll
        for (int off = 1; off < 16; off <<= 1) mx = fmaxf(mx, __shfl_xor(mx, off));
        m[r] = mx;
    }
    if (lr == 0) redbuf[0][w][lg*4+0] = m[0];
    if (lr == 1) redbuf[0][w][lg*4+1] = m[1];
    if (lr == 2) redbuf[0][w][lg*4+2] = m[2];
    if (lr == 3) redbuf[0][w][lg*4+3] = m[3];
    __syncthreads();
    float s[4];
    #pragma unroll
    for (int r = 0; r < 4; ++r) {
        const int rr = lg*4 + r;
        const float mx = fmaxf(fmaxf(redbuf[0][0][rr], redbuf[0][1][rr]),
                               fmaxf(redbuf[0][2][rr], redbuf[0][3][rr]));
        float sum = 0.f;
        #pragma unroll
        for (int t = 0; t < 8; ++t) {
            const float e = __expf(acc[t][r] - mx);
            acc[t][r] = e;
            sum += e;
        }
        #pragma unroll
        for (int off = 1; off < 16; off <<= 1) sum += __shfl_xor(sum, off);
        s[r] = sum;
    }
    if (lr == 0) redbuf[1][w][lg*4+0] = s[0];
    if (lr == 1) redbuf[1][w][lg*4+1] = s[1];
    if (lr == 2) redbuf[1][w][lg*4+2] = s[2];
    if (lr == 3) redbuf[1][w][lg*4+3] = s[3];
    __syncthreads();

    float* arow = attn_out + ((size_t)(h*NB + b)*SEQ + q0)*SEQ + w*128;
    #pragma unroll
    for (int r = 0; r < 4; ++r) {
        const int rr = lg*4 + r;
        const float inv = 1.0f / (redbuf[1][0][rr] + redbuf[1][1][rr] +
                                  redbuf[1][2][rr] + redbuf[1][3][rr]);
        #pragma unroll
        for (int t = 0; t < 8; ++t) {
            const float p = acc[t][r] * inv;
            arow[(size_t)rr*SEQ + t*16 + lr] = p;
            const int col = w*128 + t*16 + lr;
            int byte = rr*1024 + col*2;
            byte ^= (rr & 7) << 4;
            *(__hip_bfloat16*)((char*)P_lds + byte) = __float2bfloat16(p);
        }
    }
    __syncthreads();

    f32x4 oa = (f32x4){0.f, 0.f, 0.f, 0.f};
    f32x4 ob = (f32x4){0.f, 0.f, 0.f, 0.f};
    const size_t vbase = ((size_t)(b*NH + h)*DHEAD + w*16 + lr)*SEQ;
    #pragma unroll
    for (int ks = 0; ks < 16; ks += 2) {
        int byte0 = lr*1024 + ks*64 + lg*16;
        byte0 ^= (lr & 7) << 4;
        const bf16x8 pa0 = *(const bf16x8*)((char*)P_lds + byte0);
        const bf16x8 pb0 = *(const bf16x8*)(vhT + vbase + ks*32 + lg*8);
        oa = __builtin_amdgcn_mfma_f32_16x16x32_bf16(pa0, pb0, oa, 0, 0, 0);
        int byte1 = lr*1024 + (ks+1)*64 + lg*16;
        byte1 ^= (lr & 7) << 4;
        const bf16x8 pa1 = *(const bf16x8*)((char*)P_lds + byte1);
        const bf16x8 pb1 = *(const bf16x8*)(vhT + vbase + (ks+1)*32 + lg*8);
        ob = __builtin_amdgcn_mfma_f32_16x16x32_bf16(pa1, pb1, ob, 0, 0, 0);
    }
    #pragma unroll
    for (int r = 0; r < 4; ++r) {
        dynb[(size_t)(b*SEQ + q0 + lg*4 + r)*DIM + h*DHEAD + w*16 + lr]
            = __float2bfloat16(oa[r] + ob[r]);
    }
}

// ---------------------------------------------------------------------------
extern "C" void kernel_launch(void* const* d_in, const int* in_sizes, int n_in,
                              void* d_out, int out_size, void* d_ws, size_t ws_size,
                              hipStream_t stream) {
    const float* q    = (const float*)d_in[0];
    const float* k    = (const float*)d_in[1];
    const float* v    = (const float*)d_in[2];
    const float* Wq   = (const float*)d_in[3];
    const float* Wk   = (const float*)d_in[4];
    const float* Wv   = (const float*)d_in[5];
    const float* fc1  = (const float*)d_in[6];
    const float* fc2  = (const float*)d_in[7];
    const float* ln1g = (const float*)d_in[8];
    const float* ln1b = (const float*)d_in[9];
    const float* ln2g = (const float*)d_in[10];
    const float* ln2b = (const float*)d_in[11];
    const float* ln3g = (const float*)d_in[12];
    const float* ln3b = (const float*)d_in[13];

    const size_t DD = (size_t)DIM*DIM;       // 262144
    const size_t MD = (size_t)MROWS*DIM;     // 4194304
    __hip_bfloat16* Wall = (__hip_bfloat16*)d_ws;       // 5*DD bf16 = 2.5MB
    __hip_bfloat16* qnb  = Wall + 5*DD;
    __hip_bfloat16* knb  = qnb + MD;
    __hip_bfloat16* vnb  = knb + MD;
    __hip_bfloat16* qhb  = vnb + MD;
    __hip_bfloat16* khb  = qhb + MD;
    __hip_bfloat16* vhT  = khb + MD;         // total ~53MB
    __hip_bfloat16* vhb  = qnb;              // reuse: qnb dead after gemm(q)
    __hip_bfloat16* dynb = knb;              // reuse: knb dead after gemm(k)

    float* outDyn  = (float*)d_out;
    float* outStat = outDyn + MD;
    float* outAttn = outStat + MD;

    ln_fused_kernel<<<dim3(MROWS, 3), 128, 0, stream>>>(
        q, k, v, ln1g, ln1b, ln2g, ln2b, ln3g, ln3b, qnb, knb, vnb);
    wconv_kernel<<<dim3(256, 5), 256, 0, stream>>>(Wq, Wk, Wv, fc1, fc2, Wall);

    const dim3 gg(MROWS/128, DIM/128);   // 64 x 4
    gemm_mfma_kernel<false,true,false><<<gg, 256, 0, stream>>>(
        qnb, Wall + 0*DD, nullptr, qhb, nullptr);
    gemm_mfma_kernel<false,true,false><<<gg, 256, 0, stream>>>(
        knb, Wall + 1*DD, nullptr, khb, nullptr);
    gemm_mfma_kernel<false,true,true><<<gg, 256, 0, stream>>>(
        vnb, Wall + 2*DD, nullptr, vhb, vhT);

    attn_mfma_kernel<<<dim3(SEQ/16, NH, NB), 256, 0, stream>>>(
        qhb, khb, vhT, outAttn, dynb);

    gemm_mfma_kernel<true,false,false><<<gg, 256, 0, stream>>>(
        dynb, Wall + 3*DD, outDyn, nullptr, nullptr);
    gemm_mfma_kernel<true,false,false><<<gg, 256, 0, stream>>>(
        vhb, Wall + 4*DD, outStat, nullptr, nullptr);
}

// Round 4
// 335.399 us; speedup vs baseline: 3.5867x; 1.0702x over previous
//
#include <hip/hip_runtime.h>
#include <hip/hip_bf16.h>
#include <math.h>

#define NB 16
#define SEQ 512
#define DIM 512
#define NH 8
#define DHEAD 64
#define MROWS (NB*SEQ)   // 8192

typedef __bf16 bf16x8 __attribute__((ext_vector_type(8)));
typedef float  f32x4  __attribute__((ext_vector_type(4)));

typedef __attribute__((address_space(1))) const unsigned int gu32c;
typedef __attribute__((address_space(3))) unsigned int lu32;

__device__ __forceinline__ void gload_lds16(const void* g, void* l) {
    __builtin_amdgcn_global_load_lds((gu32c*)g, (lu32*)l, 16, 0, 0);
}

// ---------------------------------------------------------------------------
// Kernel 1: fused LayerNorm + bf16 cast. One block per (row, which).
// ---------------------------------------------------------------------------
__global__ __launch_bounds__(128)
void ln_fused_kernel(const float* __restrict__ q, const float* __restrict__ k,
                     const float* __restrict__ v,
                     const float* __restrict__ g0, const float* __restrict__ b0,
                     const float* __restrict__ g1, const float* __restrict__ b1,
                     const float* __restrict__ g2, const float* __restrict__ b2,
                     __hip_bfloat16* __restrict__ qn, __hip_bfloat16* __restrict__ kn,
                     __hip_bfloat16* __restrict__ vn) {
    const int row = blockIdx.x, which = blockIdx.y;
    const float* src = which==0 ? q : (which==1 ? k : v);
    const float* gp  = which==0 ? g0 : (which==1 ? g1 : g2);
    const float* bp  = which==0 ? b0 : (which==1 ? b1 : b2);
    __hip_bfloat16* dst = which==0 ? qn : (which==1 ? kn : vn);
    const int t = threadIdx.x;
    float4 a = *(const float4*)(src + (size_t)row*DIM + t*4);
    float s  = a.x + a.y + a.z + a.w;
    float ss = a.x*a.x + a.y*a.y + a.z*a.z + a.w*a.w;
    #pragma unroll
    for (int off = 32; off > 0; off >>= 1) {
        s  += __shfl_down(s,  off);
        ss += __shfl_down(ss, off);
    }
    __shared__ float red[4];
    if ((t & 63) == 0) { red[(t>>6)*2 + 0] = s; red[(t>>6)*2 + 1] = ss; }
    __syncthreads();
    const float S = red[0] + red[2], SS = red[1] + red[3];
    const float mean = S * (1.0f/DIM);
    const float rstd = rsqrtf(SS * (1.0f/DIM) - mean*mean + 1e-5f);
    const float4 gv = *(const float4*)(gp + t*4);
    const float4 bv = *(const float4*)(bp + t*4);
    union { ushort4 u; __hip_bfloat16 h[4]; } o;
    o.h[0] = __float2bfloat16((a.x-mean)*rstd*gv.x + bv.x);
    o.h[1] = __float2bfloat16((a.y-mean)*rstd*gv.y + bv.y);
    o.h[2] = __float2bfloat16((a.z-mean)*rstd*gv.z + bv.z);
    o.h[3] = __float2bfloat16((a.w-mean)*rstd*gv.w + bv.w);
    *(ushort4*)(dst + (size_t)row*DIM + t*4) = o.u;
}

// ---------------------------------------------------------------------------
// Kernel 2: fp32 -> bf16 cast of the 5 weight matrices (each 512x512).
// ---------------------------------------------------------------------------
__global__ __launch_bounds__(256)
void wconv_kernel(const float* __restrict__ w0, const float* __restrict__ w1,
                  const float* __restrict__ w2, const float* __restrict__ w3,
                  const float* __restrict__ w4, __hip_bfloat16* __restrict__ out) {
    const int m = blockIdx.y;
    const float* src = (m==0)?w0:(m==1)?w1:(m==2)?w2:(m==3)?w3:w4;
    __hip_bfloat16* dst = out + (size_t)m*DIM*DIM;
    const int i = (blockIdx.x*256 + threadIdx.x)*4;
    float4 x = *(const float4*)(src + i);
    union { ushort4 u; __hip_bfloat16 h[4]; } r;
    r.h[0]=__float2bfloat16(x.x); r.h[1]=__float2bfloat16(x.y);
    r.h[2]=__float2bfloat16(x.z); r.h[3]=__float2bfloat16(x.w);
    *(ushort4*)(dst + i) = r.u;
}

// ---------------------------------------------------------------------------
// Shared MFMA GEMM inner loop (m97 structure): 128x128 tile, BK=32, 4 waves,
// global_load_lds w16, linear LDS, 16 MFMA + 8 ds_read_b128 / wave / K-step.
// ---------------------------------------------------------------------------
__device__ __forceinline__ void gemm_core(const __hip_bfloat16* __restrict__ A,
                                          const __hip_bfloat16* __restrict__ W,
                                          __hip_bfloat16* Al, __hip_bfloat16* Bl,
                                          int tid, int bm, int bn,
                                          f32x4 (&acc)[4][4]) {
    const int l = tid&63, lr = l&15, lg = l>>4;
    const int w = tid>>6, wr = w>>1, wc = w&1;
    const int grow = tid>>2, gslot = tid&3;
    const __hip_bfloat16* Ag = A + (size_t)(bm*128 + grow)*DIM + gslot*8;
    const __hip_bfloat16* Wg = W + (size_t)(bn*128 + grow)*DIM + gslot*8;
    for (int kt = 0; kt < 16; ++kt) {
        __syncthreads();
        gload_lds16(Ag + kt*32,           (char*)Al + tid*16);
        gload_lds16(Ag + kt*32 + 64*DIM,  (char*)Al + 4096 + tid*16);
        gload_lds16(Wg + kt*32,           (char*)Bl + tid*16);
        gload_lds16(Wg + kt*32 + 64*DIM,  (char*)Bl + 4096 + tid*16);
        __syncthreads();
        bf16x8 af[4], bg[4];
        #pragma unroll
        for (int mi=0; mi<4; ++mi)
            af[mi] = *(const bf16x8*)((char*)Al + (wr*64 + mi*16 + lr)*64 + lg*16);
        #pragma unroll
        for (int nj=0; nj<4; ++nj)
            bg[nj] = *(const bf16x8*)((char*)Bl + (wc*64 + nj*16 + lr)*64 + lg*16);
        #pragma unroll
        for (int mi=0; mi<4; ++mi)
            #pragma unroll
            for (int nj=0; nj<4; ++nj)
                acc[mi][nj] = __builtin_amdgcn_mfma_f32_16x16x32_bf16(
                    af[mi], bg[nj], acc[mi][nj], 0, 0, 0);
    }
}

// ---------------------------------------------------------------------------
// Kernel 3a: batched QKV projection. z=0 -> qhb, z=1 -> khb,
// z=2 -> vhb (row-major) + vhT (per-head transposed).
// ---------------------------------------------------------------------------
__global__ __launch_bounds__(256, 3)
void gemm_qkv_kernel(const __hip_bfloat16* __restrict__ Abase,
                     const __hip_bfloat16* __restrict__ Wall,
                     __hip_bfloat16* __restrict__ qkout,
                     __hip_bfloat16* __restrict__ vhb,
                     __hip_bfloat16* __restrict__ vhT) {
    __shared__ __hip_bfloat16 Al[128*32];
    __shared__ __hip_bfloat16 Bl[128*32];
    const int tid = threadIdx.x;
    const int bm = blockIdx.x, bn = blockIdx.y, z = blockIdx.z;
    const size_t MD = (size_t)MROWS*DIM, DD = (size_t)DIM*DIM;
    const __hip_bfloat16* A = Abase + (size_t)z*MD;
    const __hip_bfloat16* W = Wall + (size_t)z*DD;
    f32x4 acc[4][4];
    #pragma unroll
    for (int mi=0; mi<4; ++mi)
        #pragma unroll
        for (int nj=0; nj<4; ++nj) acc[mi][nj] = (f32x4){0.f,0.f,0.f,0.f};
    gemm_core(A, W, Al, Bl, tid, bm, bn, acc);

    const int l = tid&63, lr = l&15, lg = l>>4;
    const int w = tid>>6, wr = w>>1, wc = w&1;
    __hip_bfloat16* dst = (z < 2) ? (qkout + (size_t)z*MD) : vhb;
    #pragma unroll
    for (int mi=0; mi<4; ++mi) {
        #pragma unroll
        for (int nj=0; nj<4; ++nj) {
            #pragma unroll
            for (int r=0; r<4; ++r) {
                const int row = bm*128 + wr*64 + mi*16 + lg*4 + r;
                const int col = bn*128 + wc*64 + nj*16 + lr;
                const __hip_bfloat16 bv = __float2bfloat16(acc[mi][nj][r]);
                dst[(size_t)row*DIM + col] = bv;
                if (z == 2) {
                    const int b = row >> 9, sp = row & 511;
                    const int h = col >> 6, d = col & 63;
                    vhT[((size_t)(b*NH + h)*DHEAD + d)*SEQ + sp] = bv;
                }
            }
        }
    }
}

// ---------------------------------------------------------------------------
// Kernel 3b: batched FC. z=0: outDyn = dynb @ fc1^T; z=1: outStat = vhb @ fc2^T.
// ---------------------------------------------------------------------------
__global__ __launch_bounds__(256, 3)
void gemm_fc_kernel(const __hip_bfloat16* __restrict__ dynb,
                    const __hip_bfloat16* __restrict__ vhb,
                    const __hip_bfloat16* __restrict__ Wfc,
                    float* __restrict__ outbase) {
    __shared__ __hip_bfloat16 Al[128*32];
    __shared__ __hip_bfloat16 Bl[128*32];
    const int tid = threadIdx.x;
    const int bm = blockIdx.x, bn = blockIdx.y, z = blockIdx.z;
    const size_t MD = (size_t)MROWS*DIM, DD = (size_t)DIM*DIM;
    const __hip_bfloat16* A = z ? vhb : dynb;
    const __hip_bfloat16* W = Wfc + (size_t)z*DD;
    f32x4 acc[4][4];
    #pragma unroll
    for (int mi=0; mi<4; ++mi)
        #pragma unroll
        for (int nj=0; nj<4; ++nj) acc[mi][nj] = (f32x4){0.f,0.f,0.f,0.f};
    gemm_core(A, W, Al, Bl, tid, bm, bn, acc);

    const int l = tid&63, lr = l&15, lg = l>>4;
    const int w = tid>>6, wr = w>>1, wc = w&1;
    float* dst = outbase + (size_t)z*MD;
    #pragma unroll
    for (int mi=0; mi<4; ++mi)
        #pragma unroll
        for (int nj=0; nj<4; ++nj)
            #pragma unroll
            for (int r=0; r<4; ++r) {
                const int row = bm*128 + wr*64 + mi*16 + lg*4 + r;
                const int col = bn*128 + wc*64 + nj*16 + lr;
                dst[(size_t)row*DIM + col] = acc[mi][nj][r];
            }
}

// ---------------------------------------------------------------------------
// Kernel 4: MFMA attention (validated). dynpre out in bf16.
// ---------------------------------------------------------------------------
__global__ __launch_bounds__(256)
void attn_mfma_kernel(const __hip_bfloat16* __restrict__ qhb,
                      const __hip_bfloat16* __restrict__ khb,
                      const __hip_bfloat16* __restrict__ vhT,
                      float* __restrict__ attn_out,
                      __hip_bfloat16* __restrict__ dynb) {
    __shared__ __hip_bfloat16 P_lds[16*512];   // 16KB, XOR-swizzled
    __shared__ float redbuf[2][4][16];
    const int tid = threadIdx.x;
    const int qt = blockIdx.x, h = blockIdx.y, b = blockIdx.z;
    const int q0 = qt * 16;
    const int w  = tid >> 6;
    const int l  = tid & 63;
    const int lr = l & 15;
    const int lg = l >> 4;

    const size_t qoff = (size_t)(b*SEQ + q0 + lr)*DIM + h*DHEAD + lg*8;
    const bf16x8 qf0 = *(const bf16x8*)(qhb + qoff);
    const bf16x8 qf1 = *(const bf16x8*)(qhb + qoff + 32);

    f32x4 acc[8];
    #pragma unroll
    for (int t = 0; t < 8; ++t) acc[t] = (f32x4){0.f, 0.f, 0.f, 0.f};
    #pragma unroll
    for (int t = 0; t < 8; ++t) {
        const int kbase = w*128 + t*16;
        const size_t koff = (size_t)(b*SEQ + kbase + lr)*DIM + h*DHEAD + lg*8;
        const bf16x8 kf0 = *(const bf16x8*)(khb + koff);
        const bf16x8 kf1 = *(const bf16x8*)(khb + koff + 32);
        acc[t] = __builtin_amdgcn_mfma_f32_16x16x32_bf16(qf0, kf0, acc[t], 0, 0, 0);
        acc[t] = __builtin_amdgcn_mfma_f32_16x16x32_bf16(qf1, kf1, acc[t], 0, 0, 0);
    }

    float m[4];
    #pragma unroll
    for (int r = 0; r < 4; ++r) {
        const int grow = q0 + lg*4 + r;
        float mx = -1e30f;
        #pragma unroll
        for (int t = 0; t < 8; ++t) {
            float vv = acc[t][r] * 0.125f;
            if (w*128 + t*16 + lr == grow) vv = -1e30f;
            acc[t][r] = vv;
            mx = fmaxf(mx, vv);
        }
        #pragma unroll
        for (int off = 1; off < 16; off <<= 1) mx = fmaxf(mx, __shfl_xor(mx, off));
        m[r] = mx;
    }
    if (lr == 0) redbuf[0][w][lg*4+0] = m[0];
    if (lr == 1) redbuf[0][w][lg*4+1] = m[1];
    if (lr == 2) redbuf[0][w][lg*4+2] = m[2];
    if (lr == 3) redbuf[0][w][lg*4+3] = m[3];
    __syncthreads();
    float s[4];
    #pragma unroll
    for (int r = 0; r < 4; ++r) {
        const int rr = lg*4 + r;
        const float mx = fmaxf(fmaxf(redbuf[0][0][rr], redbuf[0][1][rr]),
                               fmaxf(redbuf[0][2][rr], redbuf[0][3][rr]));
        float sum = 0.f;
        #pragma unroll
        for (int t = 0; t < 8; ++t) {
            const float e = __expf(acc[t][r] - mx);
            acc[t][r] = e;
            sum += e;
        }
        #pragma unroll
        for (int off = 1; off < 16; off <<= 1) sum += __shfl_xor(sum, off);
        s[r] = sum;
    }
    if (lr == 0) redbuf[1][w][lg*4+0] = s[0];
    if (lr == 1) redbuf[1][w][lg*4+1] = s[1];
    if (lr == 2) redbuf[1][w][lg*4+2] = s[2];
    if (lr == 3) redbuf[1][w][lg*4+3] = s[3];
    __syncthreads();

    float* arow = attn_out + ((size_t)(h*NB + b)*SEQ + q0)*SEQ + w*128;
    #pragma unroll
    for (int r = 0; r < 4; ++r) {
        const int rr = lg*4 + r;
        const float inv = 1.0f / (redbuf[1][0][rr] + redbuf[1][1][rr] +
                                  redbuf[1][2][rr] + redbuf[1][3][rr]);
        #pragma unroll
        for (int t = 0; t < 8; ++t) {
            const float p = acc[t][r] * inv;
            arow[(size_t)rr*SEQ + t*16 + lr] = p;
            const int col = w*128 + t*16 + lr;
            int byte = rr*1024 + col*2;
            byte ^= (rr & 7) << 4;
            *(__hip_bfloat16*)((char*)P_lds + byte) = __float2bfloat16(p);
        }
    }
    __syncthreads();

    f32x4 oa = (f32x4){0.f, 0.f, 0.f, 0.f};
    f32x4 ob = (f32x4){0.f, 0.f, 0.f, 0.f};
    const size_t vbase = ((size_t)(b*NH + h)*DHEAD + w*16 + lr)*SEQ;
    #pragma unroll
    for (int ks = 0; ks < 16; ks += 2) {
        int byte0 = lr*1024 + ks*64 + lg*16;
        byte0 ^= (lr & 7) << 4;
        const bf16x8 pa0 = *(const bf16x8*)((char*)P_lds + byte0);
        const bf16x8 pb0 = *(const bf16x8*)(vhT + vbase + ks*32 + lg*8);
        oa = __builtin_amdgcn_mfma_f32_16x16x32_bf16(pa0, pb0, oa, 0, 0, 0);
        int byte1 = lr*1024 + (ks+1)*64 + lg*16;
        byte1 ^= (lr & 7) << 4;
        const bf16x8 pa1 = *(const bf16x8*)((char*)P_lds + byte1);
        const bf16x8 pb1 = *(const bf16x8*)(vhT + vbase + (ks+1)*32 + lg*8);
        ob = __builtin_amdgcn_mfma_f32_16x16x32_bf16(pa1, pb1, ob, 0, 0, 0);
    }
    #pragma unroll
    for (int r = 0; r < 4; ++r) {
        dynb[(size_t)(b*SEQ + q0 + lg*4 + r)*DIM + h*DHEAD + w*16 + lr]
            = __float2bfloat16(oa[r] + ob[r]);
    }
}

// ---------------------------------------------------------------------------
extern "C" void kernel_launch(void* const* d_in, const int* in_sizes, int n_in,
                              void* d_out, int out_size, void* d_ws, size_t ws_size,
                              hipStream_t stream) {
    const float* q    = (const float*)d_in[0];
    const float* k    = (const float*)d_in[1];
    const float* v    = (const float*)d_in[2];
    const float* Wq   = (const float*)d_in[3];
    const float* Wk   = (const float*)d_in[4];
    const float* Wv   = (const float*)d_in[5];
    const float* fc1  = (const float*)d_in[6];
    const float* fc2  = (const float*)d_in[7];
    const float* ln1g = (const float*)d_in[8];
    const float* ln1b = (const float*)d_in[9];
    const float* ln2g = (const float*)d_in[10];
    const float* ln2b = (const float*)d_in[11];
    const float* ln3g = (const float*)d_in[12];
    const float* ln3b = (const float*)d_in[13];

    const size_t DD = (size_t)DIM*DIM;       // 262144
    const size_t MD = (size_t)MROWS*DIM;     // 4194304
    __hip_bfloat16* Wall = (__hip_bfloat16*)d_ws;       // 5*DD = 2.5MB
    __hip_bfloat16* qnb  = Wall + 5*DD;      // qn,kn,vn contiguous (batched A)
    __hip_bfloat16* knb  = qnb + MD;
    __hip_bfloat16* vnb  = knb + MD;
    __hip_bfloat16* qhb  = vnb + MD;         // qh,kh contiguous (batched out)
    __hip_bfloat16* khb  = qhb + MD;
    __hip_bfloat16* vhT  = khb + MD;
    __hip_bfloat16* vhb  = vhT + MD;         // private (no alias: z-batch races)
    __hip_bfloat16* dynb = vhb + MD;         // total ~70MB

    float* outDyn  = (float*)d_out;
    float* outAttn = outDyn + 2*MD;

    ln_fused_kernel<<<dim3(MROWS, 3), 128, 0, stream>>>(
        q, k, v, ln1g, ln1b, ln2g, ln2b, ln3g, ln3b, qnb, knb, vnb);
    wconv_kernel<<<dim3(256, 5), 256, 0, stream>>>(Wq, Wk, Wv, fc1, fc2, Wall);

    gemm_qkv_kernel<<<dim3(MROWS/128, DIM/128, 3), 256, 0, stream>>>(
        qnb, Wall, qhb, vhb, vhT);

    attn_mfma_kernel<<<dim3(SEQ/16, NH, NB), 256, 0, stream>>>(
        qhb, khb, vhT, outAttn, dynb);

    gemm_fc_kernel<<<dim3(MROWS/128, DIM/128, 2), 256, 0, stream>>>(
        dynb, vhb, Wall + 3*DD, outDyn);
}

// Round 6
// 324.118 us; speedup vs baseline: 3.7116x; 1.0348x over previous
//
#include <hip/hip_runtime.h>
#include <hip/hip_bf16.h>
#include <math.h>

#define NB 16
#define SEQ 512
#define DIM 512
#define NH 8
#define DHEAD 64
#define MROWS (NB*SEQ)   // 8192

typedef __bf16 bf16x8 __attribute__((ext_vector_type(8)));
typedef float  f32x4  __attribute__((ext_vector_type(4)));

typedef __attribute__((address_space(1))) const unsigned int gu32c;
typedef __attribute__((address_space(3))) unsigned int lu32;

__device__ __forceinline__ void gload_lds16(const void* g, void* l) {
    __builtin_amdgcn_global_load_lds((gu32c*)g, (lu32*)l, 16, 0, 0);
}

// ---------------------------------------------------------------------------
// Kernel 1: fused LayerNorm + bf16 cast. One block per (row, which).
// ---------------------------------------------------------------------------
__global__ __launch_bounds__(128)
void ln_fused_kernel(const float* __restrict__ q, const float* __restrict__ k,
                     const float* __restrict__ v,
                     const float* __restrict__ g0, const float* __restrict__ b0,
                     const float* __restrict__ g1, const float* __restrict__ b1,
                     const float* __restrict__ g2, const float* __restrict__ b2,
                     __hip_bfloat16* __restrict__ qn, __hip_bfloat16* __restrict__ kn,
                     __hip_bfloat16* __restrict__ vn) {
    const int row = blockIdx.x, which = blockIdx.y;
    const float* src = which==0 ? q : (which==1 ? k : v);
    const float* gp  = which==0 ? g0 : (which==1 ? g1 : g2);
    const float* bp  = which==0 ? b0 : (which==1 ? b1 : b2);
    __hip_bfloat16* dst = which==0 ? qn : (which==1 ? kn : vn);
    const int t = threadIdx.x;
    float4 a = *(const float4*)(src + (size_t)row*DIM + t*4);
    float s  = a.x + a.y + a.z + a.w;
    float ss = a.x*a.x + a.y*a.y + a.z*a.z + a.w*a.w;
    #pragma unroll
    for (int off = 32; off > 0; off >>= 1) {
        s  += __shfl_down(s,  off);
        ss += __shfl_down(ss, off);
    }
    __shared__ float red[4];
    if ((t & 63) == 0) { red[(t>>6)*2 + 0] = s; red[(t>>6)*2 + 1] = ss; }
    __syncthreads();
    const float S = red[0] + red[2], SS = red[1] + red[3];
    const float mean = S * (1.0f/DIM);
    const float rstd = rsqrtf(SS * (1.0f/DIM) - mean*mean + 1e-5f);
    const float4 gv = *(const float4*)(gp + t*4);
    const float4 bv = *(const float4*)(bp + t*4);
    union { ushort4 u; __hip_bfloat16 h[4]; } o;
    o.h[0] = __float2bfloat16((a.x-mean)*rstd*gv.x + bv.x);
    o.h[1] = __float2bfloat16((a.y-mean)*rstd*gv.y + bv.y);
    o.h[2] = __float2bfloat16((a.z-mean)*rstd*gv.z + bv.z);
    o.h[3] = __float2bfloat16((a.w-mean)*rstd*gv.w + bv.w);
    *(ushort4*)(dst + (size_t)row*DIM + t*4) = o.u;
}

// ---------------------------------------------------------------------------
// Kernel 2: fp32 -> bf16 cast of the 5 weight matrices (each 512x512).
// ---------------------------------------------------------------------------
__global__ __launch_bounds__(256)
void wconv_kernel(const float* __restrict__ w0, const float* __restrict__ w1,
                  const float* __restrict__ w2, const float* __restrict__ w3,
                  const float* __restrict__ w4, __hip_bfloat16* __restrict__ out) {
    const int m = blockIdx.y;
    const float* src = (m==0)?w0:(m==1)?w1:(m==2)?w2:(m==3)?w3:w4;
    __hip_bfloat16* dst = out + (size_t)m*DIM*DIM;
    const int i = (blockIdx.x*256 + threadIdx.x)*4;
    float4 x = *(const float4*)(src + i);
    union { ushort4 u; __hip_bfloat16 h[4]; } r;
    r.h[0]=__float2bfloat16(x.x); r.h[1]=__float2bfloat16(x.y);
    r.h[2]=__float2bfloat16(x.z); r.h[3]=__float2bfloat16(x.w);
    *(ushort4*)(dst + i) = r.u;
}

// ---------------------------------------------------------------------------
// Shared MFMA GEMM inner loop, v2: 2-phase double-buffered prefetch.
// 128x128 tile, BK=32, 4 waves. Per K-step: STAGE(next tile -> other buf)
// FIRST, then ds_read + 16 MFMA on current buf, then ONE __syncthreads()
// (its vmcnt(0)/lgkmcnt(0) drain covers both buffer handoffs). Loads are in
// flight during the whole compute phase instead of being serially drained
// between two barriers (T3 minimum-2-phase recipe).
// ---------------------------------------------------------------------------
__device__ __forceinline__ void gemm_core(const __hip_bfloat16* __restrict__ A,
                                          const __hip_bfloat16* __restrict__ W,
                                          __hip_bfloat16 (&Al)[2][128*32],
                                          __hip_bfloat16 (&Bl)[2][128*32],
                                          int tid, int bm, int bn,
                                          f32x4 (&acc)[4][4]) {
    const int l = tid&63, lr = l&15, lg = l>>4;
    const int w = tid>>6, wr = w>>1, wc = w&1;
    const int grow = tid>>2, gslot = tid&3;
    const __hip_bfloat16* Ag = A + (size_t)(bm*128 + grow)*DIM + gslot*8;
    const __hip_bfloat16* Wg = W + (size_t)(bn*128 + grow)*DIM + gslot*8;

    // prologue: stage tile 0 into buf 0
    gload_lds16(Ag,           (char*)Al[0] + tid*16);
    gload_lds16(Ag + 64*DIM,  (char*)Al[0] + 4096 + tid*16);
    gload_lds16(Wg,           (char*)Bl[0] + tid*16);
    gload_lds16(Wg + 64*DIM,  (char*)Bl[0] + 4096 + tid*16);
    __syncthreads();

    int cur = 0;
    for (int kt = 0; kt < 16; ++kt) {
        if (kt < 15) {   // stage next tile into the other buffer
            const int nx = cur ^ 1;
            gload_lds16(Ag + (kt+1)*32,           (char*)Al[nx] + tid*16);
            gload_lds16(Ag + (kt+1)*32 + 64*DIM,  (char*)Al[nx] + 4096 + tid*16);
            gload_lds16(Wg + (kt+1)*32,           (char*)Bl[nx] + tid*16);
            gload_lds16(Wg + (kt+1)*32 + 64*DIM,  (char*)Bl[nx] + 4096 + tid*16);
        }
        bf16x8 af[4], bg[4];
        #pragma unroll
        for (int mi=0; mi<4; ++mi)
            af[mi] = *(const bf16x8*)((char*)Al[cur] + (wr*64 + mi*16 + lr)*64 + lg*16);
        #pragma unroll
        for (int nj=0; nj<4; ++nj)
            bg[nj] = *(const bf16x8*)((char*)Bl[cur] + (wc*64 + nj*16 + lr)*64 + lg*16);
        #pragma unroll
        for (int mi=0; mi<4; ++mi)
            #pragma unroll
            for (int nj=0; nj<4; ++nj)
                acc[mi][nj] = __builtin_amdgcn_mfma_f32_16x16x32_bf16(
                    af[mi], bg[nj], acc[mi][nj], 0, 0, 0);
        __syncthreads();   // drain: next-tile loads landed; this tile's reads done
        cur ^= 1;
    }
}

// ---------------------------------------------------------------------------
// Kernel 3a: batched QKV projection. z=0 -> qhb, z=1 -> khb,
// z=2 -> vhb (row-major) + vhT (per-head transposed, ushort4-packed stores).
// ---------------------------------------------------------------------------
__global__ __launch_bounds__(256, 3)
void gemm_qkv_kernel(const __hip_bfloat16* __restrict__ Abase,
                     const __hip_bfloat16* __restrict__ Wall,
                     __hip_bfloat16* __restrict__ qkout,
                     __hip_bfloat16* __restrict__ vhb,
                     __hip_bfloat16* __restrict__ vhT) {
    __shared__ __hip_bfloat16 Al[2][128*32];
    __shared__ __hip_bfloat16 Bl[2][128*32];
    const int tid = threadIdx.x;
    const int bm = blockIdx.x, bn = blockIdx.y, z = blockIdx.z;
    const size_t MD = (size_t)MROWS*DIM, DD = (size_t)DIM*DIM;
    const __hip_bfloat16* A = Abase + (size_t)z*MD;
    const __hip_bfloat16* W = Wall + (size_t)z*DD;
    f32x4 acc[4][4];
    #pragma unroll
    for (int mi=0; mi<4; ++mi)
        #pragma unroll
        for (int nj=0; nj<4; ++nj) acc[mi][nj] = (f32x4){0.f,0.f,0.f,0.f};
    gemm_core(A, W, Al, Bl, tid, bm, bn, acc);

    const int l = tid&63, lr = l&15, lg = l>>4;
    const int w = tid>>6, wr = w>>1, wc = w&1;
    __hip_bfloat16* dst = (z < 2) ? (qkout + (size_t)z*MD) : vhb;
    #pragma unroll
    for (int mi=0; mi<4; ++mi) {
        #pragma unroll
        for (int nj=0; nj<4; ++nj) {
            const int col = bn*128 + wc*64 + nj*16 + lr;
            const int row0 = bm*128 + wr*64 + mi*16 + lg*4;
            union { ushort4 u; __hip_bfloat16 h[4]; } pk;
            #pragma unroll
            for (int r=0; r<4; ++r) {
                const __hip_bfloat16 bv = __float2bfloat16(acc[mi][nj][r]);
                pk.h[r] = bv;
                dst[(size_t)(row0 + r)*DIM + col] = bv;
            }
            if (z == 2) {
                // row0..row0+3 are 4 consecutive seq positions of one batch:
                // contiguous in vhT -> single 8B store.
                const int b = row0 >> 9, sp = row0 & 511;
                const int h = col >> 6, d = col & 63;
                *(ushort4*)(vhT + ((size_t)(b*NH + h)*DHEAD + d)*SEQ + sp) = pk.u;
            }
        }
    }
}

// ---------------------------------------------------------------------------
// Kernel 3b: batched FC. z=0: outDyn = dynb @ fc1^T; z=1: outStat = vhb @ fc2^T.
// ---------------------------------------------------------------------------
__global__ __launch_bounds__(256, 3)
void gemm_fc_kernel(const __hip_bfloat16* __restrict__ dynb,
                    const __hip_bfloat16* __restrict__ vhb,
                    const __hip_bfloat16* __restrict__ Wfc,
                    float* __restrict__ outbase) {
    __shared__ __hip_bfloat16 Al[2][128*32];
    __shared__ __hip_bfloat16 Bl[2][128*32];
    const int tid = threadIdx.x;
    const int bm = blockIdx.x, bn = blockIdx.y, z = blockIdx.z;
    const size_t MD = (size_t)MROWS*DIM, DD = (size_t)DIM*DIM;
    const __hip_bfloat16* A = z ? vhb : dynb;
    const __hip_bfloat16* W = Wfc + (size_t)z*DD;
    f32x4 acc[4][4];
    #pragma unroll
    for (int mi=0; mi<4; ++mi)
        #pragma unroll
        for (int nj=0; nj<4; ++nj) acc[mi][nj] = (f32x4){0.f,0.f,0.f,0.f};
    gemm_core(A, W, Al, Bl, tid, bm, bn, acc);

    const int l = tid&63, lr = l&15, lg = l>>4;
    const int w = tid>>6, wr = w>>1, wc = w&1;
    float* dst = outbase + (size_t)z*MD;
    #pragma unroll
    for (int mi=0; mi<4; ++mi)
        #pragma unroll
        for (int nj=0; nj<4; ++nj)
            #pragma unroll
            for (int r=0; r<4; ++r) {
                const int row = bm*128 + wr*64 + mi*16 + lg*4 + r;
                const int col = bn*128 + wc*64 + nj*16 + lr;
                dst[(size_t)row*DIM + col] = acc[mi][nj][r];
            }
}

// ---------------------------------------------------------------------------
// Kernel 4: MFMA attention (validated, unchanged). dynpre out in bf16.
// ---------------------------------------------------------------------------
__global__ __launch_bounds__(256)
void attn_mfma_kernel(const __hip_bfloat16* __restrict__ qhb,
                      const __hip_bfloat16* __restrict__ khb,
                      const __hip_bfloat16* __restrict__ vhT,
                      float* __restrict__ attn_out,
                      __hip_bfloat16* __restrict__ dynb) {
    __shared__ __hip_bfloat16 P_lds[16*512];   // 16KB, XOR-swizzled
    __shared__ float redbuf[2][4][16];
    const int tid = threadIdx.x;
    const int qt = blockIdx.x, h = blockIdx.y, b = blockIdx.z;
    const int q0 = qt * 16;
    const int w  = tid >> 6;
    const int l  = tid & 63;
    const int lr = l & 15;
    const int lg = l >> 4;

    const size_t qoff = (size_t)(b*SEQ + q0 + lr)*DIM + h*DHEAD + lg*8;
    const bf16x8 qf0 = *(const bf16x8*)(qhb + qoff);
    const bf16x8 qf1 = *(const bf16x8*)(qhb + qoff + 32);

    f32x4 acc[8];
    #pragma unroll
    for (int t = 0; t < 8; ++t) acc[t] = (f32x4){0.f, 0.f, 0.f, 0.f};
    #pragma unroll
    for (int t = 0; t < 8; ++t) {
        const int kbase = w*128 + t*16;
        const size_t koff = (size_t)(b*SEQ + kbase + lr)*DIM + h*DHEAD + lg*8;
        const bf16x8 kf0 = *(const bf16x8*)(khb + koff);
        const bf16x8 kf1 = *(const bf16x8*)(khb + koff + 32);
        acc[t] = __builtin_amdgcn_mfma_f32_16x16x32_bf16(qf0, kf0, acc[t], 0, 0, 0);
        acc[t] = __builtin_amdgcn_mfma_f32_16x16x32_bf16(qf1, kf1, acc[t], 0, 0, 0);
    }

    float m[4];
    #pragma unroll
    for (int r = 0; r < 4; ++r) {
        const int grow = q0 + lg*4 + r;
        float mx = -1e30f;
        #pragma unroll
        for (int t = 0; t < 8; ++t) {
            float vv = acc[t][r] * 0.125f;
            if (w*128 + t*16 + lr == grow) vv = -1e30f;
            acc[t][r] = vv;
            mx = fmaxf(mx, vv);
        }
        #pragma unroll
        for (int off = 1; off < 16; off <<= 1) mx = fmaxf(mx, __shfl_xor(mx, off));
        m[r] = mx;
    }
    if (lr == 0) redbuf[0][w][lg*4+0] = m[0];
    if (lr == 1) redbuf[0][w][lg*4+1] = m[1];
    if (lr == 2) redbuf[0][w][lg*4+2] = m[2];
    if (lr == 3) redbuf[0][w][lg*4+3] = m[3];
    __syncthreads();
    float s[4];
    #pragma unroll
    for (int r = 0; r < 4; ++r) {
        const int rr = lg*4 + r;
        const float mx = fmaxf(fmaxf(redbuf[0][0][rr], redbuf[0][1][rr]),
                               fmaxf(redbuf[0][2][rr], redbuf[0][3][rr]));
        float sum = 0.f;
        #pragma unroll
        for (int t = 0; t < 8; ++t) {
            const float e = __expf(acc[t][r] - mx);
            acc[t][r] = e;
            sum += e;
        }
        #pragma unroll
        for (int off = 1; off < 16; off <<= 1) sum += __shfl_xor(sum, off);
        s[r] = sum;
    }
    if (lr == 0) redbuf[1][w][lg*4+0] = s[0];
    if (lr == 1) redbuf[1][w][lg*4+1] = s[1];
    if (lr == 2) redbuf[1][w][lg*4+2] = s[2];
    if (lr == 3) redbuf[1][w][lg*4+3] = s[3];
    __syncthreads();

    float* arow = attn_out + ((size_t)(h*NB + b)*SEQ + q0)*SEQ + w*128;
    #pragma unroll
    for (int r = 0; r < 4; ++r) {
        const int rr = lg*4 + r;
        const float inv = 1.0f / (redbuf[1][0][rr] + redbuf[1][1][rr] +
                                  redbuf[1][2][rr] + redbuf[1][3][rr]);
        #pragma unroll
        for (int t = 0; t < 8; ++t) {
            const float p = acc[t][r] * inv;
            arow[(size_t)rr*SEQ + t*16 + lr] = p;
            const int col = w*128 + t*16 + lr;
            int byte = rr*1024 + col*2;
            byte ^= (rr & 7) << 4;
            *(__hip_bfloat16*)((char*)P_lds + byte) = __float2bfloat16(p);
        }
    }
    __syncthreads();

    f32x4 oa = (f32x4){0.f, 0.f, 0.f, 0.f};
    f32x4 ob = (f32x4){0.f, 0.f, 0.f, 0.f};
    const size_t vbase = ((size_t)(b*NH + h)*DHEAD + w*16 + lr)*SEQ;
    #pragma unroll
    for (int ks = 0; ks < 16; ks += 2) {
        int byte0 = lr*1024 + ks*64 + lg*16;
        byte0 ^= (lr & 7) << 4;
        const bf16x8 pa0 = *(const bf16x8*)((char*)P_lds + byte0);
        const bf16x8 pb0 = *(const bf16x8*)(vhT + vbase + ks*32 + lg*8);
        oa = __builtin_amdgcn_mfma_f32_16x16x32_bf16(pa0, pb0, oa, 0, 0, 0);
        int byte1 = lr*1024 + (ks+1)*64 + lg*16;
        byte1 ^= (lr & 7) << 4;
        const bf16x8 pa1 = *(const bf16x8*)((char*)P_lds + byte1);
        const bf16x8 pb1 = *(const bf16x8*)(vhT + vbase + (ks+1)*32 + lg*8);
        ob = __builtin_amdgcn_mfma_f32_16x16x32_bf16(pa1, pb1, ob, 0, 0, 0);
    }
    #pragma unroll
    for (int r = 0; r < 4; ++r) {
        dynb[(size_t)(b*SEQ + q0 + lg*4 + r)*DIM + h*DHEAD + w*16 + lr]
            = __float2bfloat16(oa[r] + ob[r]);
    }
}

// ---------------------------------------------------------------------------
extern "C" void kernel_launch(void* const* d_in, const int* in_sizes, int n_in,
                              void* d_out, int out_size, void* d_ws, size_t ws_size,
                              hipStream_t stream) {
    const float* q    = (const float*)d_in[0];
    const float* k    = (const float*)d_in[1];
    const float* v    = (const float*)d_in[2];
    const float* Wq   = (const float*)d_in[3];
    const float* Wk   = (const float*)d_in[4];
    const float* Wv   = (const float*)d_in[5];
    const float* fc1  = (const float*)d_in[6];
    const float* fc2  = (const float*)d_in[7];
    const float* ln1g = (const float*)d_in[8];
    const float* ln1b = (const float*)d_in[9];
    const float* ln2g = (const float*)d_in[10];
    const float* ln2b = (const float*)d_in[11];
    const float* ln3g = (const float*)d_in[12];
    const float* ln3b = (const float*)d_in[13];

    const size_t DD = (size_t)DIM*DIM;       // 262144
    const size_t MD = (size_t)MROWS*DIM;     // 4194304
    __hip_bfloat16* Wall = (__hip_bfloat16*)d_ws;       // 5*DD = 2.5MB
    __hip_bfloat16* qnb  = Wall + 5*DD;      // qn,kn,vn contiguous (batched A)
    __hip_bfloat16* knb  = qnb + MD;
    __hip_bfloat16* vnb  = knb + MD;
    __hip_bfloat16* qhb  = vnb + MD;         // qh,kh contiguous (batched out)
    __hip_bfloat16* khb  = qhb + MD;
    __hip_bfloat16* vhT  = khb + MD;
    __hip_bfloat16* vhb  = vhT + MD;         // private (no alias: z-batch races)
    __hip_bfloat16* dynb = vhb + MD;         // total ~70MB

    float* outDyn  = (float*)d_out;
    float* outAttn = outDyn + 2*MD;

    ln_fused_kernel<<<dim3(MROWS, 3), 128, 0, stream>>>(
        q, k, v, ln1g, ln1b, ln2g, ln2b, ln3g, ln3b, qnb, knb, vnb);
    wconv_kernel<<<dim3(256, 5), 256, 0, stream>>>(Wq, Wk, Wv, fc1, fc2, Wall);

    gemm_qkv_kernel<<<dim3(MROWS/128, DIM/128, 3), 256, 0, stream>>>(
        qnb, Wall, qhb, vhb, vhT);

    attn_mfma_kernel<<<dim3(SEQ/16, NH, NB), 256, 0, stream>>>(
        qhb, khb, vhT, outAttn, dynb);

    gemm_fc_kernel<<<dim3(MROWS/128, DIM/128, 2), 256, 0, stream>>>(
        dynb, vhb, Wall + 3*DD, outDyn);
}